// Round 1
// baseline (386.902 us; speedup 1.0000x reference)
//
#include <hip/hip_runtime.h>
#include <hip/hip_bf16.h>

// Problem constants (fixed by reference): B=2, BEV=128, Q=16384, C=256,
// H=8, L=1, P=4, D=32. spatial_shapes == [[128,128]] (hardcoded).
#define Q_TOT 32768        // B*Q rows
#define CC 256
#define GRID_W 128
#define GRID_H 128

#define BM 64
#define BN 64
#define BK 16

// Generic tiled fp32 GEMM: C[M,N] = (A (+A2)) @ B + bias (+res)
// A: M x K row-major, B: K x N row-major. M % 64 == 0, K % 16 == 0, N % 4 == 0.
__global__ __launch_bounds__(256)
void gemm_f32(const float* __restrict__ A, const float* __restrict__ A2,
              const float* __restrict__ Bm, const float* __restrict__ bias,
              const float* __restrict__ res, float* __restrict__ C,
              int M, int N, int K)
{
    __shared__ float As[BK][BM + 4];   // k-major (transposed), padded: 16B-aligned rows
    __shared__ float Bs[BK][BN];
    const int row0 = blockIdx.y * BM;
    const int col0 = blockIdx.x * BN;
    const int tid = threadIdx.x;
    const int tx = tid & 15;
    const int ty = tid >> 4;

    float acc[4][4] = {};

    for (int k0 = 0; k0 < K; k0 += BK) {
        // ---- load A tile (BM x BK), each thread one float4 of consecutive k
        {
            const int idx = tid * 4;          // 0..1023
            const int r = idx / BK;           // row in tile
            const int kk = idx % BK;          // multiple of 4
            const float* src = A + (size_t)(row0 + r) * K + (k0 + kk);
            float4 v = *(const float4*)src;
            if (A2) {
                float4 w = *(const float4*)(A2 + (size_t)(row0 + r) * K + (k0 + kk));
                v.x += w.x; v.y += w.y; v.z += w.z; v.w += w.w;
            }
            As[kk + 0][r] = v.x;
            As[kk + 1][r] = v.y;
            As[kk + 2][r] = v.z;
            As[kk + 3][r] = v.w;
        }
        // ---- load B tile (BK x BN)
        {
            const int idx = tid * 4;
            const int kk = idx / BN;          // 0..15
            const int c = idx % BN;           // multiple of 4
            const int gc = col0 + c;
            float4 v = make_float4(0.f, 0.f, 0.f, 0.f);
            if (gc < N)
                v = *(const float4*)(Bm + (size_t)(k0 + kk) * N + gc);
            *(float4*)&Bs[kk][c] = v;
        }
        __syncthreads();
        #pragma unroll
        for (int kk = 0; kk < BK; ++kk) {
            float4 a = *(const float4*)&As[kk][ty * 4];
            float4 b = *(const float4*)&Bs[kk][tx * 4];
            float av[4] = {a.x, a.y, a.z, a.w};
            float bv4[4] = {b.x, b.y, b.z, b.w};
            #pragma unroll
            for (int i = 0; i < 4; ++i)
                #pragma unroll
                for (int j = 0; j < 4; ++j)
                    acc[i][j] += av[i] * bv4[j];
        }
        __syncthreads();
    }

    // ---- epilogue: bias + residual, float4 stores
    const int c = col0 + tx * 4;
    if (c < N) {
        float4 bb = make_float4(0.f, 0.f, 0.f, 0.f);
        if (bias) bb = *(const float4*)(bias + c);
        #pragma unroll
        for (int i = 0; i < 4; ++i) {
            const int r = row0 + ty * 4 + i;
            float4 v;
            v.x = acc[i][0] + bb.x;
            v.y = acc[i][1] + bb.y;
            v.z = acc[i][2] + bb.z;
            v.w = acc[i][3] + bb.w;
            if (res) {
                float4 rr = *(const float4*)(res + (size_t)r * N + c);
                v.x += rr.x; v.y += rr.y; v.z += rr.z; v.w += rr.w;
            }
            *(float4*)(C + (size_t)r * N + c) = v;
        }
    }
}

// Bilinear deformable sampling. One block per query row (b*Q+q), 256 threads:
// thread = (h = tid>>5, d = tid&31). Produces sampled[b*Q+q][h*32+d].
__global__ __launch_bounds__(256)
void sample_kernel(const float* __restrict__ v2,    // (B, 16384, 256)
                   const float* __restrict__ offr,  // (B*Q, 64)
                   const float* __restrict__ wraw,  // (B*Q, 32)
                   const float* __restrict__ ref,   // (B*Q, 2)
                   float* __restrict__ out)         // (B*Q, 256)
{
    const int q = blockIdx.x;           // 0..32767
    const int b = q >> 14;              // Q = 16384
    const int tid = threadIdx.x;
    const int h = tid >> 5;
    const int d = tid & 31;

    // softmax over the 4 taps of this head (redundant across the 32 d-lanes)
    const float* wr = wraw + (size_t)q * 32 + h * 4;
    float w0 = wr[0], w1 = wr[1], w2 = wr[2], w3 = wr[3];
    float m = fmaxf(fmaxf(w0, w1), fmaxf(w2, w3));
    float e0 = expf(w0 - m), e1 = expf(w1 - m), e2 = expf(w2 - m), e3 = expf(w3 - m);
    float inv = 1.f / (e0 + e1 + e2 + e3);
    float aw[4] = {e0 * inv, e1 * inv, e2 * inv, e3 * inv};

    const float rx = ref[(size_t)q * 2 + 0];
    const float ry = ref[(size_t)q * 2 + 1];
    const float* offp = offr + (size_t)q * 64 + h * 8;
    const float* vb = v2 + (size_t)b * 16384 * 256 + h * 32 + d;

    float acc = 0.f;
    #pragma unroll
    for (int p = 0; p < 4; ++p) {
        float lx = rx + offp[p * 2 + 0] * (1.f / GRID_W);
        float ly = ry + offp[p * 2 + 1] * (1.f / GRID_H);
        float x = lx * (float)GRID_W - 0.5f;
        float y = ly * (float)GRID_H - 0.5f;
        float x0f = floorf(x), y0f = floorf(y);
        float dx = x - x0f, dy = y - y0f;
        int x0 = (int)x0f, y0 = (int)y0f;
        int x1 = x0 + 1, y1 = y0 + 1;
        bool xv0 = (x0 >= 0) & (x0 < GRID_W);
        bool xv1 = (x1 >= 0) & (x1 < GRID_W);
        bool yv0 = (y0 >= 0) & (y0 < GRID_H);
        bool yv1 = (y1 >= 0) & (y1 < GRID_H);
        float v00 = (xv0 && yv0) ? vb[(size_t)(y0 * GRID_W + x0) * 256] : 0.f;
        float v10 = (xv1 && yv0) ? vb[(size_t)(y0 * GRID_W + x1) * 256] : 0.f;
        float v01 = (xv0 && yv1) ? vb[(size_t)(y1 * GRID_W + x0) * 256] : 0.f;
        float v11 = (xv1 && yv1) ? vb[(size_t)(y1 * GRID_W + x1) * 256] : 0.f;
        float samp = v00 * (1.f - dx) * (1.f - dy)
                   + v10 * dx * (1.f - dy)
                   + v01 * (1.f - dx) * dy
                   + v11 * dx * dy;
        acc += aw[p] * samp;
    }
    out[(size_t)q * 256 + h * 32 + d] = acc;
}

extern "C" void kernel_launch(void* const* d_in, const int* in_sizes, int n_in,
                              void* d_out, int out_size, void* d_ws, size_t ws_size,
                              hipStream_t stream) {
    const float* query     = (const float*)d_in[0];
    const float* value     = (const float*)d_in[1];
    const float* identity  = (const float*)d_in[2];
    const float* query_pos = (const float*)d_in[3];
    const float* refpts    = (const float*)d_in[4];
    // d_in[5] spatial_shapes, d_in[6] level_start_index: constants, hardcoded
    const float* Wv   = (const float*)d_in[7];
    const float* bv   = (const float*)d_in[8];
    const float* Woff = (const float*)d_in[9];
    const float* boff = (const float*)d_in[10];
    const float* Ww   = (const float*)d_in[11];
    const float* bw   = (const float*)d_in[12];
    const float* Wo   = (const float*)d_in[13];
    const float* bo   = (const float*)d_in[14];
    float* out = (float*)d_out;

    char* ws = (char*)d_ws;
    float* v2   = (float*)(ws);                                  // 32768*256*4 = 33554432
    float* offr = (float*)(ws + 33554432);                       // 32768*64*4  =  8388608
    float* wr   = (float*)(ws + 33554432 + 8388608);             // 32768*32*4  =  4194304
    float* samp = (float*)(ws + 33554432 + 8388608 + 4194304);   // 32768*256*4 = 33554432

    // 1) v2 = value @ Wv + bv
    gemm_f32<<<dim3(4, 512), 256, 0, stream>>>(value, nullptr, Wv, bv, nullptr, v2,
                                               Q_TOT, 256, 256);
    // 2) offr = (query + query_pos) @ Woff + boff
    gemm_f32<<<dim3(1, 512), 256, 0, stream>>>(query, query_pos, Woff, boff, nullptr, offr,
                                               Q_TOT, 64, 256);
    // 3) wr = (query + query_pos) @ Ww + bw
    gemm_f32<<<dim3(1, 512), 256, 0, stream>>>(query, query_pos, Ww, bw, nullptr, wr,
                                               Q_TOT, 32, 256);
    // 4) deformable bilinear sampling -> samp
    sample_kernel<<<dim3(Q_TOT), 256, 0, stream>>>(v2, offr, wr, refpts, samp);
    // 5) out = samp @ Wo + bo + identity
    gemm_f32<<<dim3(4, 512), 256, 0, stream>>>(samp, nullptr, Wo, bo, identity, out,
                                               Q_TOT, 256, 256);
}

// Round 2
// 349.122 us; speedup vs baseline: 1.1082x; 1.1082x over previous
//
#include <hip/hip_runtime.h>
#include <hip/hip_bf16.h>
#include <stdint.h>

// Problem constants (fixed by reference): B=2, BEV=128, Q=16384, C=256,
// H=8, L=1, P=4, D=32. spatial_shapes == [[128,128]] (hardcoded).
#define Q_TOT 32768        // B*Q rows
#define CC 256
#define GRID_W 128
#define GRID_H 128

typedef __attribute__((ext_vector_type(8))) short short8;   // 8 bf16 = 4 VGPRs
typedef __attribute__((ext_vector_type(4))) float floatx4;  // MFMA accumulator

// ---------- helpers ----------
__device__ __forceinline__ ushort f2bf(float f) {
    union { float f; uint32_t u; } v; v.f = f;
    uint32_t r = (v.u + 0x7fffu + ((v.u >> 16) & 1u)) >> 16;   // RNE
    return (ushort)r;
}
__device__ __forceinline__ float bf2f(ushort s) {
    union { uint32_t u; float f; } v; v.u = ((uint32_t)s) << 16;
    return v.f;
}
// async global->LDS, 16B per lane. LDS dest must be wave-uniform.
__device__ __forceinline__ void async_load16(const void* g, void* l) {
    __builtin_amdgcn_global_load_lds(
        reinterpret_cast<const __attribute__((address_space(1))) uint32_t*>(
            reinterpret_cast<uintptr_t>(g)),
        reinterpret_cast<__attribute__((address_space(3))) uint32_t*>(
            reinterpret_cast<uintptr_t>(l)),
        16, 0, 0);
}

// ---------- prep: qsum = bf16(query+query_pos), vbf = bf16(value) ----------
__global__ __launch_bounds__(256)
void prep_convert(const float* __restrict__ q, const float* __restrict__ qp,
                  const float* __restrict__ val,
                  ushort* __restrict__ qsum, ushort* __restrict__ vbf)
{
    const int total = (Q_TOT * CC) / 4;     // float4 units per tensor
    for (int idx = blockIdx.x * blockDim.x + threadIdx.x; idx < 2 * total;
         idx += gridDim.x * blockDim.x) {
        if (idx < total) {
            float4 a = ((const float4*)q)[idx];
            float4 b = ((const float4*)qp)[idx];
            ushort4 o;
            o.x = f2bf(a.x + b.x); o.y = f2bf(a.y + b.y);
            o.z = f2bf(a.z + b.z); o.w = f2bf(a.w + b.w);
            ((ushort4*)qsum)[idx] = o;
        } else {
            int j = idx - total;
            float4 a = ((const float4*)val)[j];
            ushort4 o;
            o.x = f2bf(a.x); o.y = f2bf(a.y); o.z = f2bf(a.z); o.w = f2bf(a.w);
            ((ushort4*)vbf)[j] = o;
        }
    }
}

// ---------- prep: transposed bf16 weights + combined bias ----------
// WvT[256][256], WoT[256][256], WowT[96][256] (rows 0..63 = Woff^T, 64..95 = Ww^T),
// bias_ow[96] = {boff, bw}
__global__ __launch_bounds__(256)
void prep_weights(const float* __restrict__ Wv, const float* __restrict__ Wo,
                  const float* __restrict__ Woff, const float* __restrict__ Ww,
                  const float* __restrict__ boff, const float* __restrict__ bw,
                  ushort* __restrict__ WvT, ushort* __restrict__ WoT,
                  ushort* __restrict__ WowT, float* __restrict__ bias_ow)
{
    int idx = blockIdx.x * blockDim.x + threadIdx.x;
    if (idx < 65536) {
        int n = idx >> 8, k = idx & 255;
        WvT[idx] = f2bf(Wv[k * 256 + n]);
    } else if (idx < 131072) {
        int t = idx - 65536; int n = t >> 8, k = t & 255;
        WoT[t] = f2bf(Wo[k * 256 + n]);
    } else if (idx < 155648) {
        int t = idx - 131072; int n = t >> 8, k = t & 255;
        float v = (n < 64) ? Woff[k * 64 + n] : Ww[k * 32 + (n - 64)];
        WowT[t] = f2bf(v);
    } else if (idx < 155744) {
        int t = idx - 155648;
        bias_ow[t] = (t < 64) ? boff[t] : bw[t - 64];
    }
}

// ---------- bf16 MFMA GEMM: C[M,N] = A[M,K] @ Bt[N,K]^T + bias (+res) ----------
// 256 threads = 4 waves, wave grid WAVE_M x WAVE_N. BK = 32.
template <int BM, int BN, int WAVE_M, int WAVE_N, bool OUT_BF16>
__global__ __launch_bounds__(256)
void gemm_bf16(const ushort* __restrict__ A, const ushort* __restrict__ Bt,
               const float* __restrict__ bias, const float* __restrict__ res,
               void* __restrict__ Cout, int M, int N, int K)
{
    constexpr int TM = BM / WAVE_M / 16;   // MFMA row-tiles per wave
    constexpr int TN = BN / WAVE_N / 16;   // MFMA col-tiles per wave
    __shared__ ushort As[BM * 32];
    __shared__ ushort Bs[BN * 32];

    const int tid = threadIdx.x;
    const int lane = tid & 63;
    const int wave = tid >> 6;
    const int wm = wave / WAVE_N;
    const int wn = wave % WAVE_N;
    const int quad = lane >> 4;
    const int m16 = lane & 15;
    const int lrow = lane >> 2;          // staging: row within a 16-row group
    const int lkk = (lane & 3) * 8;      // staging: k element offset

    const int row0 = blockIdx.y * BM;
    const int col0 = blockIdx.x * BN;

    floatx4 acc[TM][TN] = {};

    for (int k0 = 0; k0 < K; k0 += 32) {
        // stage A (BM x 32) and Bt (BN x 32), 16 rows (1 KiB) per instruction
        #pragma unroll
        for (int i = wave; i < BM / 16; i += 4) {
            const ushort* src = A + (size_t)(row0 + i * 16 + lrow) * K + (k0 + lkk);
            async_load16(src, &As[i * 16 * 32]);
        }
        #pragma unroll
        for (int i = wave; i < BN / 16; i += 4) {
            const ushort* src = Bt + (size_t)(col0 + i * 16 + lrow) * K + (k0 + lkk);
            async_load16(src, &Bs[i * 16 * 32]);
        }
        __syncthreads();

        short8 af[TM], bf[TN];
        #pragma unroll
        for (int i = 0; i < TM; ++i)
            af[i] = *(const short8*)&As[(wm * TM * 16 + i * 16 + m16) * 32 + quad * 8];
        #pragma unroll
        for (int j = 0; j < TN; ++j)
            bf[j] = *(const short8*)&Bs[(wn * TN * 16 + j * 16 + m16) * 32 + quad * 8];
        #pragma unroll
        for (int i = 0; i < TM; ++i)
            #pragma unroll
            for (int j = 0; j < TN; ++j)
                acc[i][j] = __builtin_amdgcn_mfma_f32_16x16x32_bf16(
                    af[i], bf[j], acc[i][j], 0, 0, 0);
        __syncthreads();
    }

    // epilogue: C/D layout col = lane&15, row = quad*4 + reg
    #pragma unroll
    for (int i = 0; i < TM; ++i) {
        #pragma unroll
        for (int j = 0; j < TN; ++j) {
            const int gcol = col0 + wn * TN * 16 + j * 16 + m16;
            const float bb = bias[gcol];
            #pragma unroll
            for (int r = 0; r < 4; ++r) {
                const int grow = row0 + wm * TM * 16 + i * 16 + quad * 4 + r;
                float v = acc[i][j][r] + bb;
                if (res) v += res[(size_t)grow * N + gcol];
                if constexpr (OUT_BF16)
                    ((ushort*)Cout)[(size_t)grow * N + gcol] = f2bf(v);
                else
                    ((float*)Cout)[(size_t)grow * N + gcol] = v;
            }
        }
    }
}

// ---------- bilinear deformable sampling (bf16 in/out) ----------
// block = query row; thread = (h = tid>>5, d = tid&31)
__global__ __launch_bounds__(256)
void sample_kernel(const ushort* __restrict__ v2,   // (B,16384,256) bf16
                   const ushort* __restrict__ ow,   // (B*Q,96) bf16: off(64)|w(32)
                   const float* __restrict__ ref,   // (B*Q,2)
                   ushort* __restrict__ out)        // (B*Q,256) bf16
{
    const int q = blockIdx.x;
    const int b = q >> 14;
    const int tid = threadIdx.x;
    const int h = tid >> 5;
    const int d = tid & 31;

    const ushort* wr = ow + (size_t)q * 96 + 64 + h * 4;
    float w0 = bf2f(wr[0]), w1 = bf2f(wr[1]), w2 = bf2f(wr[2]), w3 = bf2f(wr[3]);
    float m = fmaxf(fmaxf(w0, w1), fmaxf(w2, w3));
    float e0 = __expf(w0 - m), e1 = __expf(w1 - m), e2 = __expf(w2 - m), e3 = __expf(w3 - m);
    float inv = 1.f / (e0 + e1 + e2 + e3);
    float aw[4] = {e0 * inv, e1 * inv, e2 * inv, e3 * inv};

    const float rx = ref[(size_t)q * 2 + 0];
    const float ry = ref[(size_t)q * 2 + 1];
    const ushort* offp = ow + (size_t)q * 96 + h * 8;
    const ushort* vb = v2 + (size_t)b * 16384 * 256 + h * 32 + d;

    float acc = 0.f;
    #pragma unroll
    for (int p = 0; p < 4; ++p) {
        float x = (rx + bf2f(offp[p * 2 + 0]) * (1.f / GRID_W)) * (float)GRID_W - 0.5f;
        float y = (ry + bf2f(offp[p * 2 + 1]) * (1.f / GRID_H)) * (float)GRID_H - 0.5f;
        float x0f = floorf(x), y0f = floorf(y);
        float dx = x - x0f, dy = y - y0f;
        int x0 = (int)x0f, y0 = (int)y0f;
        int x1 = x0 + 1, y1 = y0 + 1;
        bool xv0 = (x0 >= 0) & (x0 < GRID_W);
        bool xv1 = (x1 >= 0) & (x1 < GRID_W);
        bool yv0 = (y0 >= 0) & (y0 < GRID_H);
        bool yv1 = (y1 >= 0) & (y1 < GRID_H);
        float v00 = (xv0 && yv0) ? bf2f(vb[(size_t)(y0 * GRID_W + x0) * 256]) : 0.f;
        float v10 = (xv1 && yv0) ? bf2f(vb[(size_t)(y0 * GRID_W + x1) * 256]) : 0.f;
        float v01 = (xv0 && yv1) ? bf2f(vb[(size_t)(y1 * GRID_W + x0) * 256]) : 0.f;
        float v11 = (xv1 && yv1) ? bf2f(vb[(size_t)(y1 * GRID_W + x1) * 256]) : 0.f;
        float samp = v00 * (1.f - dx) * (1.f - dy) + v10 * dx * (1.f - dy)
                   + v01 * (1.f - dx) * dy + v11 * dx * dy;
        acc += aw[p] * samp;
    }
    out[(size_t)q * 256 + h * 32 + d] = f2bf(acc);
}

extern "C" void kernel_launch(void* const* d_in, const int* in_sizes, int n_in,
                              void* d_out, int out_size, void* d_ws, size_t ws_size,
                              hipStream_t stream) {
    const float* query     = (const float*)d_in[0];
    const float* value     = (const float*)d_in[1];
    const float* identity  = (const float*)d_in[2];
    const float* query_pos = (const float*)d_in[3];
    const float* refpts    = (const float*)d_in[4];
    const float* Wv   = (const float*)d_in[7];
    const float* bv   = (const float*)d_in[8];
    const float* Woff = (const float*)d_in[9];
    const float* boff = (const float*)d_in[10];
    const float* Ww   = (const float*)d_in[11];
    const float* bw   = (const float*)d_in[12];
    const float* Wo   = (const float*)d_in[13];
    const float* bo   = (const float*)d_in[14];
    float* out = (float*)d_out;

    char* ws = (char*)d_ws;
    ushort* qsum_bf  = (ushort*)(ws);                      // 16,777,216 B
    ushort* value_bf = (ushort*)(ws + 16777216);           // 16,777,216 B
    ushort* v2_bf    = (ushort*)(ws + 33554432);           // 16,777,216 B
    ushort* ow_bf    = (ushort*)(ws + 50331648);           //  6,291,456 B
    ushort* samp_bf  = (ushort*)(ws + 56623104);           // 16,777,216 B
    ushort* WvT      = (ushort*)(ws + 73400320);           //    131,072 B
    ushort* WoT      = (ushort*)(ws + 73531392);           //    131,072 B
    ushort* WowT     = (ushort*)(ws + 73662464);           //     49,152 B
    float*  bias_ow  = (float*)(ws + 73711616);            //        384 B

    // 1) bf16 conversions of activations
    prep_convert<<<8192, 256, 0, stream>>>(query, query_pos, value, qsum_bf, value_bf);
    // 2) transposed bf16 weights + combined bias
    prep_weights<<<609, 256, 0, stream>>>(Wv, Wo, Woff, Ww, boff, bw,
                                          WvT, WoT, WowT, bias_ow);
    // 3) v2 = value @ Wv + bv  (bf16 out)
    gemm_bf16<128, 128, 2, 2, true><<<dim3(2, 256), 256, 0, stream>>>(
        value_bf, WvT, bv, nullptr, v2_bf, Q_TOT, 256, 256);
    // 4) ow = qsum @ [Woff|Ww] + [boff|bw]  (bf16 out, N=96)
    gemm_bf16<64, 96, 4, 1, true><<<dim3(1, 512), 256, 0, stream>>>(
        qsum_bf, WowT, bias_ow, nullptr, ow_bf, Q_TOT, 96, 256);
    // 5) deformable bilinear sampling -> samp (bf16)
    sample_kernel<<<dim3(Q_TOT), 256, 0, stream>>>(v2_bf, ow_bf, refpts, samp_bf);
    // 6) out = samp @ Wo + bo + identity  (fp32 out)
    gemm_bf16<128, 128, 2, 2, false><<<dim3(2, 256), 256, 0, stream>>>(
        samp_bf, WoT, bo, identity, out, Q_TOT, 256, 256);
}

// Round 3
// 268.818 us; speedup vs baseline: 1.4393x; 1.2987x over previous
//
#include <hip/hip_runtime.h>
#include <hip/hip_bf16.h>
#include <stdint.h>

// Problem constants (fixed by reference): B=2, BEV=128, Q=16384, C=256,
// H=8, L=1, P=4, D=32. spatial_shapes == [[128,128]] (hardcoded).
#define Q_TOT 32768        // B*Q rows
#define CC 256
#define GRID_W 128
#define GRID_H 128

typedef __attribute__((ext_vector_type(8))) short short8;   // 8 bf16 = 4 VGPRs
typedef __attribute__((ext_vector_type(4))) float floatx4;  // MFMA accumulator

// ---------- helpers ----------
__device__ __forceinline__ ushort f2bf(float f) {
    union { float f; uint32_t u; } v; v.f = f;
    uint32_t r = (v.u + 0x7fffu + ((v.u >> 16) & 1u)) >> 16;   // RNE
    return (ushort)r;
}
__device__ __forceinline__ float bf2f(ushort s) {
    union { uint32_t u; float f; } v; v.u = ((uint32_t)s) << 16;
    return v.f;
}
// unpack 2 bf16 packed in a uint32 -> 2 floats (2 bit-ops)
__device__ __forceinline__ void bf2x2(uint32_t u, float& lo, float& hi) {
    union { uint32_t u; float f; } a, b;
    a.u = u << 16; b.u = u & 0xffff0000u;
    lo = a.f; hi = b.f;
}
// async global->LDS, 16B per lane. LDS dest must be wave-uniform.
__device__ __forceinline__ void async_load16(const void* g, void* l) {
    __builtin_amdgcn_global_load_lds(
        reinterpret_cast<const __attribute__((address_space(1))) uint32_t*>(
            reinterpret_cast<uintptr_t>(g)),
        reinterpret_cast<__attribute__((address_space(3))) uint32_t*>(
            reinterpret_cast<uintptr_t>(l)),
        16, 0, 0);
}

// ---------- prep: qsum = bf16(query+query_pos), vbf = bf16(value) ----------
__global__ __launch_bounds__(256)
void prep_convert(const float* __restrict__ q, const float* __restrict__ qp,
                  const float* __restrict__ val,
                  ushort* __restrict__ qsum, ushort* __restrict__ vbf)
{
    const int total = (Q_TOT * CC) / 4;     // float4 units per tensor
    for (int idx = blockIdx.x * blockDim.x + threadIdx.x; idx < 2 * total;
         idx += gridDim.x * blockDim.x) {
        if (idx < total) {
            float4 a = ((const float4*)q)[idx];
            float4 b = ((const float4*)qp)[idx];
            ushort4 o;
            o.x = f2bf(a.x + b.x); o.y = f2bf(a.y + b.y);
            o.z = f2bf(a.z + b.z); o.w = f2bf(a.w + b.w);
            ((ushort4*)qsum)[idx] = o;
        } else {
            int j = idx - total;
            float4 a = ((const float4*)val)[j];
            ushort4 o;
            o.x = f2bf(a.x); o.y = f2bf(a.y); o.z = f2bf(a.z); o.w = f2bf(a.w);
            ((ushort4*)vbf)[j] = o;
        }
    }
}

// ---------- prep: transposed bf16 weights + combined bias ----------
__global__ __launch_bounds__(256)
void prep_weights(const float* __restrict__ Wv, const float* __restrict__ Wo,
                  const float* __restrict__ Woff, const float* __restrict__ Ww,
                  const float* __restrict__ boff, const float* __restrict__ bw,
                  ushort* __restrict__ WvT, ushort* __restrict__ WoT,
                  ushort* __restrict__ WowT, float* __restrict__ bias_ow)
{
    int idx = blockIdx.x * blockDim.x + threadIdx.x;
    if (idx < 65536) {
        int n = idx >> 8, k = idx & 255;
        WvT[idx] = f2bf(Wv[k * 256 + n]);
    } else if (idx < 131072) {
        int t = idx - 65536; int n = t >> 8, k = t & 255;
        WoT[t] = f2bf(Wo[k * 256 + n]);
    } else if (idx < 155648) {
        int t = idx - 131072; int n = t >> 8, k = t & 255;
        float v = (n < 64) ? Woff[k * 64 + n] : Ww[k * 32 + (n - 64)];
        WowT[t] = f2bf(v);
    } else if (idx < 155744) {
        int t = idx - 155648;
        bias_ow[t] = (t < 64) ? boff[t] : bw[t - 64];
    }
}

// ---------- bf16 MFMA GEMM: C[M,N] = A[M,K] @ Bt[N,K]^T + bias (+res) ----------
template <int BM, int BN, int WAVE_M, int WAVE_N, bool OUT_BF16>
__global__ __launch_bounds__(256)
void gemm_bf16(const ushort* __restrict__ A, const ushort* __restrict__ Bt,
               const float* __restrict__ bias, const float* __restrict__ res,
               void* __restrict__ Cout, int M, int N, int K)
{
    constexpr int TM = BM / WAVE_M / 16;   // MFMA row-tiles per wave
    constexpr int TN = BN / WAVE_N / 16;   // MFMA col-tiles per wave
    __shared__ ushort As[BM * 32];
    __shared__ ushort Bs[BN * 32];

    const int tid = threadIdx.x;
    const int lane = tid & 63;
    const int wave = tid >> 6;
    const int wm = wave / WAVE_N;
    const int wn = wave % WAVE_N;
    const int quad = lane >> 4;
    const int m16 = lane & 15;
    const int lrow = lane >> 2;          // staging: row within a 16-row group
    const int lkk = (lane & 3) * 8;      // staging: k element offset

    const int row0 = blockIdx.y * BM;
    const int col0 = blockIdx.x * BN;

    floatx4 acc[TM][TN] = {};

    for (int k0 = 0; k0 < K; k0 += 32) {
        #pragma unroll
        for (int i = wave; i < BM / 16; i += 4) {
            const ushort* src = A + (size_t)(row0 + i * 16 + lrow) * K + (k0 + lkk);
            async_load16(src, &As[i * 16 * 32]);
        }
        #pragma unroll
        for (int i = wave; i < BN / 16; i += 4) {
            const ushort* src = Bt + (size_t)(col0 + i * 16 + lrow) * K + (k0 + lkk);
            async_load16(src, &Bs[i * 16 * 32]);
        }
        __syncthreads();

        short8 af[TM], bf[TN];
        #pragma unroll
        for (int i = 0; i < TM; ++i)
            af[i] = *(const short8*)&As[(wm * TM * 16 + i * 16 + m16) * 32 + quad * 8];
        #pragma unroll
        for (int j = 0; j < TN; ++j)
            bf[j] = *(const short8*)&Bs[(wn * TN * 16 + j * 16 + m16) * 32 + quad * 8];
        #pragma unroll
        for (int i = 0; i < TM; ++i)
            #pragma unroll
            for (int j = 0; j < TN; ++j)
                acc[i][j] = __builtin_amdgcn_mfma_f32_16x16x32_bf16(
                    af[i], bf[j], acc[i][j], 0, 0, 0);
        __syncthreads();
    }

    // epilogue: C/D layout col = lane&15, row = quad*4 + reg
    #pragma unroll
    for (int i = 0; i < TM; ++i) {
        #pragma unroll
        for (int j = 0; j < TN; ++j) {
            const int gcol = col0 + wn * TN * 16 + j * 16 + m16;
            const float bb = bias[gcol];
            #pragma unroll
            for (int r = 0; r < 4; ++r) {
                const int grow = row0 + wm * TM * 16 + i * 16 + quad * 4 + r;
                float v = acc[i][j][r] + bb;
                if (res) v += res[(size_t)grow * N + gcol];
                if constexpr (OUT_BF16)
                    ((ushort*)Cout)[(size_t)grow * N + gcol] = f2bf(v);
                else
                    ((float*)Cout)[(size_t)grow * N + gcol] = v;
            }
        }
    }
}

// ---------- bilinear deformable sampling (bf16 in/out), vectorized ----------
// 256 threads handle 8 queries: thread = (ql = tid>>5, h = (tid>>2)&7, dg = tid&3).
// Each thread produces 8 channels (d = dg*8..dg*8+7) via 16B corner loads.
#define QB 8
__global__ __launch_bounds__(256)
void sample_kernel(const ushort* __restrict__ v2,   // (B,16384,256) bf16
                   const ushort* __restrict__ ow,   // (B*Q,96) bf16: off(64)|w(32)
                   const float* __restrict__ ref,   // (B*Q,2)
                   ushort* __restrict__ out)        // (B*Q,256) bf16
{
    const int tid = threadIdx.x;
    const int ql = tid >> 5;
    const int h  = (tid >> 2) & 7;
    const int dg = tid & 3;
    const int q = blockIdx.x * QB + ql;
    const int b = q >> 14;

    // offsets for this (q,h): 8 bf16 = 16B aligned
    const ushort* op = ow + (size_t)q * 96 + h * 8;
    const uint4 oraw = *(const uint4*)op;
    float offs[8];
    bf2x2(oraw.x, offs[0], offs[1]);
    bf2x2(oraw.y, offs[2], offs[3]);
    bf2x2(oraw.z, offs[4], offs[5]);
    bf2x2(oraw.w, offs[6], offs[7]);

    // attention logits: 4 bf16 = 8B
    const uint2 wraw = *(const uint2*)(ow + (size_t)q * 96 + 64 + h * 4);
    float w0, w1, w2, w3;
    bf2x2(wraw.x, w0, w1);
    bf2x2(wraw.y, w2, w3);
    float m = fmaxf(fmaxf(w0, w1), fmaxf(w2, w3));
    float e0 = __expf(w0 - m), e1 = __expf(w1 - m), e2 = __expf(w2 - m), e3 = __expf(w3 - m);
    float inv = 1.f / (e0 + e1 + e2 + e3);
    float aw[4] = {e0 * inv, e1 * inv, e2 * inv, e3 * inv};

    const float rx = ref[(size_t)q * 2 + 0];
    const float ry = ref[(size_t)q * 2 + 1];
    const ushort* vb = v2 + (size_t)b * 16384 * 256 + h * 32 + dg * 8;

    float acc[8] = {};
    #pragma unroll
    for (int p = 0; p < 4; ++p) {
        float x = rx * (float)GRID_W + offs[p * 2 + 0] - 0.5f;
        float y = ry * (float)GRID_H + offs[p * 2 + 1] - 0.5f;
        float x0f = floorf(x), y0f = floorf(y);
        float dx = x - x0f, dy = y - y0f;
        int x0 = (int)x0f, y0 = (int)y0f;
        int x1 = x0 + 1, y1 = y0 + 1;
        float vx0 = (x0 >= 0 && x0 < GRID_W) ? 1.f : 0.f;
        float vx1 = (x1 >= 0 && x1 < GRID_W) ? 1.f : 0.f;
        float vy0 = (y0 >= 0 && y0 < GRID_H) ? 1.f : 0.f;
        float vy1 = (y1 >= 0 && y1 < GRID_H) ? 1.f : 0.f;
        int xc0 = min(max(x0, 0), GRID_W - 1), xc1 = min(max(x1, 0), GRID_W - 1);
        int yc0 = min(max(y0, 0), GRID_H - 1), yc1 = min(max(y1, 0), GRID_H - 1);
        float cw00 = aw[p] * (1.f - dx) * (1.f - dy) * vx0 * vy0;
        float cw10 = aw[p] * dx * (1.f - dy) * vx1 * vy0;
        float cw01 = aw[p] * (1.f - dx) * dy * vx0 * vy1;
        float cw11 = aw[p] * dx * dy * vx1 * vy1;
        const int base0 = yc0 * GRID_W, base1 = yc1 * GRID_W;
        const uint4 r00 = *(const uint4*)(vb + (size_t)(base0 + xc0) * 256);
        const uint4 r10 = *(const uint4*)(vb + (size_t)(base0 + xc1) * 256);
        const uint4 r01 = *(const uint4*)(vb + (size_t)(base1 + xc0) * 256);
        const uint4 r11 = *(const uint4*)(vb + (size_t)(base1 + xc1) * 256);
        float lo, hi;
        bf2x2(r00.x, lo, hi); acc[0] += cw00 * lo; acc[1] += cw00 * hi;
        bf2x2(r00.y, lo, hi); acc[2] += cw00 * lo; acc[3] += cw00 * hi;
        bf2x2(r00.z, lo, hi); acc[4] += cw00 * lo; acc[5] += cw00 * hi;
        bf2x2(r00.w, lo, hi); acc[6] += cw00 * lo; acc[7] += cw00 * hi;
        bf2x2(r10.x, lo, hi); acc[0] += cw10 * lo; acc[1] += cw10 * hi;
        bf2x2(r10.y, lo, hi); acc[2] += cw10 * lo; acc[3] += cw10 * hi;
        bf2x2(r10.z, lo, hi); acc[4] += cw10 * lo; acc[5] += cw10 * hi;
        bf2x2(r10.w, lo, hi); acc[6] += cw10 * lo; acc[7] += cw10 * hi;
        bf2x2(r01.x, lo, hi); acc[0] += cw01 * lo; acc[1] += cw01 * hi;
        bf2x2(r01.y, lo, hi); acc[2] += cw01 * lo; acc[3] += cw01 * hi;
        bf2x2(r01.z, lo, hi); acc[4] += cw01 * lo; acc[5] += cw01 * hi;
        bf2x2(r01.w, lo, hi); acc[6] += cw01 * lo; acc[7] += cw01 * hi;
        bf2x2(r11.x, lo, hi); acc[0] += cw11 * lo; acc[1] += cw11 * hi;
        bf2x2(r11.y, lo, hi); acc[2] += cw11 * lo; acc[3] += cw11 * hi;
        bf2x2(r11.z, lo, hi); acc[4] += cw11 * lo; acc[5] += cw11 * hi;
        bf2x2(r11.w, lo, hi); acc[6] += cw11 * lo; acc[7] += cw11 * hi;
    }

    // pack 8 channels -> 16B store
    uint4 o;
    o.x = ((uint32_t)f2bf(acc[1]) << 16) | f2bf(acc[0]);
    o.y = ((uint32_t)f2bf(acc[3]) << 16) | f2bf(acc[2]);
    o.z = ((uint32_t)f2bf(acc[5]) << 16) | f2bf(acc[4]);
    o.w = ((uint32_t)f2bf(acc[7]) << 16) | f2bf(acc[6]);
    *(uint4*)(out + (size_t)q * 256 + h * 32 + dg * 8) = o;
}

extern "C" void kernel_launch(void* const* d_in, const int* in_sizes, int n_in,
                              void* d_out, int out_size, void* d_ws, size_t ws_size,
                              hipStream_t stream) {
    const float* query     = (const float*)d_in[0];
    const float* value     = (const float*)d_in[1];
    const float* identity  = (const float*)d_in[2];
    const float* query_pos = (const float*)d_in[3];
    const float* refpts    = (const float*)d_in[4];
    const float* Wv   = (const float*)d_in[7];
    const float* bv   = (const float*)d_in[8];
    const float* Woff = (const float*)d_in[9];
    const float* boff = (const float*)d_in[10];
    const float* Ww   = (const float*)d_in[11];
    const float* bw   = (const float*)d_in[12];
    const float* Wo   = (const float*)d_in[13];
    const float* bo   = (const float*)d_in[14];
    float* out = (float*)d_out;

    char* ws = (char*)d_ws;
    ushort* qsum_bf  = (ushort*)(ws);                      // 16,777,216 B
    ushort* value_bf = (ushort*)(ws + 16777216);           // 16,777,216 B
    ushort* v2_bf    = (ushort*)(ws + 33554432);           // 16,777,216 B
    ushort* ow_bf    = (ushort*)(ws + 50331648);           //  6,291,456 B
    ushort* samp_bf  = (ushort*)(ws + 56623104);           // 16,777,216 B
    ushort* WvT      = (ushort*)(ws + 73400320);           //    131,072 B
    ushort* WoT      = (ushort*)(ws + 73531392);           //    131,072 B
    ushort* WowT     = (ushort*)(ws + 73662464);           //     49,152 B
    float*  bias_ow  = (float*)(ws + 73711616);            //        384 B

    // 1) bf16 conversions of activations
    prep_convert<<<8192, 256, 0, stream>>>(query, query_pos, value, qsum_bf, value_bf);
    // 2) transposed bf16 weights + combined bias
    prep_weights<<<609, 256, 0, stream>>>(Wv, Wo, Woff, Ww, boff, bw,
                                          WvT, WoT, WowT, bias_ow);
    // 3) v2 = value @ Wv + bv  (bf16 out)
    gemm_bf16<128, 128, 2, 2, true><<<dim3(2, 256), 256, 0, stream>>>(
        value_bf, WvT, bv, nullptr, v2_bf, Q_TOT, 256, 256);
    // 4) ow = qsum @ [Woff|Ww] + [boff|bw]  (bf16 out, N=96)
    gemm_bf16<64, 96, 4, 1, true><<<dim3(1, 512), 256, 0, stream>>>(
        qsum_bf, WowT, bias_ow, nullptr, ow_bf, Q_TOT, 96, 256);
    // 5) deformable bilinear sampling -> samp (bf16)
    sample_kernel<<<dim3(Q_TOT / QB), 256, 0, stream>>>(v2_bf, ow_bf, refpts, samp_bf);
    // 6) out = samp @ Wo + bo + identity  (fp32 out)
    gemm_bf16<128, 128, 2, 2, false><<<dim3(2, 256), 256, 0, stream>>>(
        samp_bf, WoT, bo, identity, out, Q_TOT, 256, 256);
}